// Round 8
// baseline (587.967 us; speedup 1.0000x reference)
//
#include <hip/hip_runtime.h>
#include <hip/hip_bf16.h>

#define NPOS 784
#define WDIM 28

// ---------------- kernel 1: fused 1x1-conv q/k/v -> d_ws ----------------
// All fp32. Layout [bh][kl][m], m contiguous (16 floats = 64 B per row).
__global__ __launch_bounds__(256) void qkv_kernel(
    const float* __restrict__ x,
    const float* __restrict__ wq, const float* __restrict__ bq,
    const float* __restrict__ wk, const float* __restrict__ bk,
    const float* __restrict__ wv, const float* __restrict__ bv,
    float* __restrict__ Q, float* __restrict__ K, float* __restrict__ V)
{
    int idx = blockIdx.x * 256 + threadIdx.x;        // grid covers exactly 401408
    int ij = idx % NPOS;
    int oc = (idx / NPOS) & 127;
    int b  = idx / (NPOS * 128);

    float x0 = x[(b * 3 + 0) * NPOS + ij];
    float x1 = x[(b * 3 + 1) * NPOS + ij];
    float x2 = x[(b * 3 + 2) * NPOS + ij];

    float q = bq[oc] + wq[oc*3+0]*x0 + wq[oc*3+1]*x1 + wq[oc*3+2]*x2;
    float k = bk[oc] + wk[oc*3+0]*x0 + wk[oc*3+1]*x1 + wk[oc*3+2]*x2;
    float v = bv[oc] + wv[oc*3+0]*x0 + wv[oc*3+1]*x1 + wv[oc*3+2]*x2;

    int m = oc >> 3, h = oc & 7;                     // oc = m*HEADS + h
    int dst = ((b * 8 + h) * NPOS + ij) * 16 + m;
    Q[dst] = q; K[dst] = k; V[dst] = v;
}

// ---------------- kernel 2: attention, block = (b, ij), wave-owned heads ----
// Wave w processes heads {w, w+4}; no barriers inside the head loop.
// Max-free softmax: exp(s - bound) with bound = max_k(content) + rot-term
// bound (normalization cancels the constant). Content staged fp32 in a
// per-wave LDS strip [ch][s] (conflict-free broadcast reads in PV).
__global__ __launch_bounds__(256, 6) void attn_kernel(
    const float* __restrict__ Q, const float* __restrict__ K, const float* __restrict__ V,
    const float* __restrict__ w_out, const float* __restrict__ b_out,
    const float* __restrict__ rw1, const float* __restrict__ rb1,
    const float* __restrict__ rga, const float* __restrict__ rbe,
    const float* __restrict__ rw2, const float* __restrict__ rb2,
    const float* __restrict__ cw1, const float* __restrict__ cb1,
    const float* __restrict__ cga, const float* __restrict__ cbe,
    const float* __restrict__ cw2, const float* __restrict__ cb2,
    float* __restrict__ out)
{
    __shared__ float  Er[8 * 110], Ec[8 * 110];      // embed tables, transposed [m][d]
    __shared__ float  cont[4][16 * 50];              // [wave][ch*50 + s], s<49
    __shared__ float4 Rt[4][56];                     // per-wave packed rotation terms
    __shared__ float  ovs[8][4][16];                 // [h][g][m]

    const int t    = threadIdx.x;
    const int b    = blockIdx.x / NPOS;
    const int ij   = blockIdx.x % NPOS;
    const int iq   = ij / WDIM, jq = ij % WDIM;
    const int wave = t >> 6, lane = t & 63;
    const float scale = 0.57735026918962576f;        // 1/sqrt(CIN=3)

    // ---- embedding-MLP tables (once per block), transposed to [m][110] ----
    {
        int d = -1;
        const float *w1 = rw1, *b1 = rb1, *ga = rga, *be = rbe, *w2 = rw2, *b2 = rb2;
        float* E = Er;
        if (t < 110) { d = t; }
        else if (t >= 128 && t < 238) { d = t - 128; w1 = cw1; b1 = cb1; ga = cga; be = cbe; w2 = cw2; b2 = cb2; E = Ec; }
        if (d >= 0) {
            float u = (d < 55) ? (-1.0f + (float)d * (2.0f / 54.0f))
                               : -(-1.0f + (float)(d - 55) * (2.0f / 54.0f));
            float hb[16], mu = 0.0f;
#pragma unroll
            for (int c = 0; c < 16; ++c) { hb[c] = u * w1[c] + b1[c]; mu += hb[c]; }
            mu *= (1.0f / 16.0f);
            float var = 0.0f;
#pragma unroll
            for (int c = 0; c < 16; ++c) { float dv = hb[c] - mu; var += dv * dv; }
            var *= (1.0f / 16.0f);
            float rstd = rsqrtf(var + 1e-5f);
#pragma unroll
            for (int c = 0; c < 16; ++c) {
                float hn = ga[c] * (hb[c] - mu) * rstd + be[c];
                hb[c] = hn / (1.0f + __expf(-hn));
            }
#pragma unroll
            for (int m = 0; m < 8; ++m) {
                float e = b2[m];
#pragma unroll
                for (int c = 0; c < 16; ++c) e += hb[c] * w2[m * 16 + c];
                E[m * 110 + d] = e;                  // transposed
            }
        }
    }
    __syncthreads();                                 // E ready for all waves

    for (int hi = 0; hi < 2; ++hi) {
        const int h  = wave + hi * 4;
        const int bh = b * 8 + h;

        // q in registers (uniform per wave-head; L2-hot broadcast loads)
        float q[16];
        {
            const float4* qp = (const float4*)(Q + (size_t)(bh * NPOS + ij) * 16);
            float4 q0 = qp[0], q1 = qp[1], q2 = qp[2], q3 = qp[3];
            q[0]=q0.x; q[1]=q0.y; q[2]=q0.z; q[3]=q0.w;
            q[4]=q1.x; q[5]=q1.y; q[6]=q1.z; q[7]=q1.w;
            q[8]=q2.x; q[9]=q2.y; q[10]=q2.z; q[11]=q2.w;
            q[12]=q3.x; q[13]=q3.y; q[14]=q3.z; q[15]=q3.w;
        }

        // packed rotation table Rt[d] = scale*(arow[d], acol[d], arow[d+55], acol[d+55])
        // + per-component maxima (for the softmax bound)
        float4 myR = make_float4(-3.0e38f, -3.0e38f, -3.0e38f, -3.0e38f);
        if (lane < 55) {
            int d = lane;
            float ar = 0, ac = 0, ar5 = 0, ac5 = 0;
#pragma unroll
            for (int mm = 0; mm < 8; ++mm) {
                float ql = q[mm], qh = q[8 + mm];
                ar  += ql * Er[mm * 110 + d];
                ar5 += ql * Er[mm * 110 + d + 55];
                ac  += qh * Ec[mm * 110 + d];
                ac5 += qh * Ec[mm * 110 + d + 55];
            }
            myR = make_float4(ar * scale, ac * scale, ar5 * scale, ac5 * scale);
            Rt[wave][lane] = myR;
        }
#pragma unroll
        for (int off = 1; off < 64; off <<= 1) {
            myR.x = fmaxf(myR.x, __shfl_xor(myR.x, off, 64));
            myR.y = fmaxf(myR.y, __shfl_xor(myR.y, off, 64));
            myR.z = fmaxf(myR.z, __shfl_xor(myR.z, off, 64));
            myR.w = fmaxf(myR.w, __shfl_xor(myR.w, off, 64));
        }

        // phase A: content pass -> per-wave LDS strip cont[ch*50+s], track max c
        float maxc = -3.0e38f;
#pragma unroll
        for (int it = 0; it < 13; ++it) {
            int k = it * 64 + lane;
            if (k < NPOS) {
                const float4* kp = (const float4*)(K + (size_t)(bh * NPOS + k) * 16);
                float4 k0 = kp[0], k1 = kp[1], k2 = kp[2], k3 = kp[3];
                float c = q[0]*k0.x + q[1]*k0.y + q[2]*k0.z + q[3]*k0.w
                        + q[4]*k1.x + q[5]*k1.y + q[6]*k1.z + q[7]*k1.w
                        + q[8]*k2.x + q[9]*k2.y + q[10]*k2.z + q[11]*k2.w
                        + q[12]*k3.x + q[13]*k3.y + q[14]*k3.z + q[15]*k3.w;
                c *= scale;
                cont[wave][(lane & 15) * 50 + (k >> 4)] = c;
                maxc = fmaxf(maxc, c);
            }
        }
#pragma unroll
        for (int off = 1; off < 64; off <<= 1) maxc = fmaxf(maxc, __shfl_xor(maxc, off, 64));

        // phase B: PV. lane = (g = lane>>4, ch = lane&15); keys k = s*16+ch.
        // One exp per (g,key); V as 4x float4 (coalesced, L2-hot).
        const int g = lane >> 4, ch = lane & 15;
        // score_g = c + rr[g] + rc[(g+1)&3]; bound uses component maxima
        const float bndrot = ((g == 0) ? myR.x + myR.y :
                              (g == 1) ? myR.y + myR.z :
                              (g == 2) ? myR.z + myR.w :
                                         myR.w + myR.x);
        const float bound = maxc + bndrot;
        const int i1 = g, i2 = (g + 1) & 3;
        const float* RtS = (const float*)&Rt[wave][0];   // scalar view, 4 floats per d
        const float* cw  = &cont[wave][ch * 50];

        float acc[16];
#pragma unroll
        for (int m = 0; m < 16; ++m) acc[m] = 0.0f;
        float ps = 0.0f;
        for (int s = 0; s < 49; ++s) {
            int k = s * 16 + ch;
            int row = k / WDIM, col = k - row * WDIM;
            float c  = cw[s];                             // broadcast across 4 g-groups
            float tr = RtS[(row - iq + 27) * 4 + i1];     // scalar LDS, ~2-way banks
            float tc = RtS[(col - jq + 27) * 4 + i2];
            float p = __expf(c + tr + tc - bound);
            ps += p;
            const float4* vp = (const float4*)(V + (size_t)(bh * NPOS + k) * 16);
            float4 v0 = vp[0], v1 = vp[1], v2 = vp[2], v3 = vp[3];
            acc[0]  += p * v0.x; acc[1]  += p * v0.y; acc[2]  += p * v0.z; acc[3]  += p * v0.w;
            acc[4]  += p * v1.x; acc[5]  += p * v1.y; acc[6]  += p * v1.z; acc[7]  += p * v1.w;
            acc[8]  += p * v2.x; acc[9]  += p * v2.y; acc[10] += p * v2.z; acc[11] += p * v2.w;
            acc[12] += p * v3.x; acc[13] += p * v3.y; acc[14] += p * v3.z; acc[15] += p * v3.w;
        }
        // reduce across the 16-lane ch group (xor stays inside the group)
#pragma unroll
        for (int off = 1; off < 16; off <<= 1) {
            ps += __shfl_xor(ps, off, 64);
#pragma unroll
            for (int m = 0; m < 16; ++m) acc[m] += __shfl_xor(acc[m], off, 64);
        }
        if (ch == 0) {
            float inv = 1.0f / ps;
#pragma unroll
            for (int m = 0; m < 16; ++m) ovs[h][g][m] = acc[m] * inv;
        }
    }
    __syncthreads();                                 // all ovs ready

    // ---- output projection: thread = (o = t>>2, g = t&3); out (B,64,G,28,28) ----
    {
        int o = t >> 2, g = t & 3;
        float acc = b_out[o];
        const float4* wr = (const float4*)(w_out + o * 128);
#pragma unroll
        for (int c4 = 0; c4 < 32; ++c4) {
            float4 w4 = wr[c4];
            int c = c4 * 4;                          // mh = m*8 + h
            acc += w4.x * ovs[(c    ) & 7][g][(c    ) >> 3];
            acc += w4.y * ovs[(c + 1) & 7][g][(c + 1) >> 3];
            acc += w4.z * ovs[(c + 2) & 7][g][(c + 2) >> 3];
            acc += w4.w * ovs[(c + 3) & 7][g][(c + 3) >> 3];
        }
        out[((b * 64 + o) * 4 + g) * NPOS + ij] = acc;
    }
}

extern "C" void kernel_launch(void* const* d_in, const int* in_sizes, int n_in,
                              void* d_out, int out_size, void* d_ws, size_t ws_size,
                              hipStream_t stream)
{
    const float* x     = (const float*)d_in[0];
    const float* wq    = (const float*)d_in[1];
    const float* bq    = (const float*)d_in[2];
    const float* wk    = (const float*)d_in[3];
    const float* bk    = (const float*)d_in[4];
    const float* wv    = (const float*)d_in[5];
    const float* bv    = (const float*)d_in[6];
    const float* w_out = (const float*)d_in[7];
    const float* b_out = (const float*)d_in[8];
    const float* rw1 = (const float*)d_in[9];
    const float* rb1 = (const float*)d_in[10];
    const float* rga = (const float*)d_in[11];
    const float* rbe = (const float*)d_in[12];
    const float* rw2 = (const float*)d_in[13];
    const float* rb2 = (const float*)d_in[14];
    const float* cw1 = (const float*)d_in[15];
    const float* cb1 = (const float*)d_in[16];
    const float* cga = (const float*)d_in[17];
    const float* cbe = (const float*)d_in[18];
    const float* cw2 = (const float*)d_in[19];
    const float* cb2 = (const float*)d_in[20];
    // d_in[21]/d_in[22] (ridx/cidx) unused: closed-form rotation indices.

    float* Q = (float*)d_ws;                 // 3 x 401408 floats = 4.8 MB
    float* K = Q + 401408;
    float* V = K + 401408;

    qkv_kernel<<<1568, 256, 0, stream>>>(x, wq, bq, wk, bk, wv, bv, Q, K, V);
    attn_kernel<<<4 * NPOS, 256, 0, stream>>>(
        Q, K, V, w_out, b_out,
        rw1, rb1, rga, rbe, rw2, rb2,
        cw1, cb1, cga, cbe, cw2, cb2,
        (float*)d_out);
}

// Round 9
// 570.092 us; speedup vs baseline: 1.0314x; 1.0314x over previous
//
#include <hip/hip_runtime.h>
#include <hip/hip_bf16.h>

#define NPOS 784
#define WDIM 28

// ---------------- kernel 1: fused 1x1-conv q/k/v -> d_ws ----------------
// All fp32. Layout [bh][kl][m], m contiguous (16 floats = 64 B per row).
__global__ __launch_bounds__(256) void qkv_kernel(
    const float* __restrict__ x,
    const float* __restrict__ wq, const float* __restrict__ bq,
    const float* __restrict__ wk, const float* __restrict__ bk,
    const float* __restrict__ wv, const float* __restrict__ bv,
    float* __restrict__ Q, float* __restrict__ K, float* __restrict__ V)
{
    int idx = blockIdx.x * 256 + threadIdx.x;        // grid covers exactly 401408
    int ij = idx % NPOS;
    int oc = (idx / NPOS) & 127;
    int b  = idx / (NPOS * 128);

    float x0 = x[(b * 3 + 0) * NPOS + ij];
    float x1 = x[(b * 3 + 1) * NPOS + ij];
    float x2 = x[(b * 3 + 2) * NPOS + ij];

    float q = bq[oc] + wq[oc*3+0]*x0 + wq[oc*3+1]*x1 + wq[oc*3+2]*x2;
    float k = bk[oc] + wk[oc*3+0]*x0 + wk[oc*3+1]*x1 + wk[oc*3+2]*x2;
    float v = bv[oc] + wv[oc*3+0]*x0 + wv[oc*3+1]*x1 + wv[oc*3+2]*x2;

    int m = oc >> 3, h = oc & 7;                     // oc = m*HEADS + h
    int dst = ((b * 8 + h) * NPOS + ij) * 16 + m;
    Q[dst] = q; K[dst] = k; V[dst] = v;
}

// ---------------- kernel 2: attention, block = (b, 4-query tile) ----------------
// Wave w owns query ij0+w. All 4 waves process the SAME head per iteration
// (lockstep barrier) so K/V float4 streams are shared through L1.
// Max-free softmax: exp(s - bound), bound = max_k(content) + rot-term bound.
__global__ __launch_bounds__(256, 4) void attn_kernel(
    const float* __restrict__ Q, const float* __restrict__ K, const float* __restrict__ V,
    const float* __restrict__ w_out, const float* __restrict__ b_out,
    const float* __restrict__ rw1, const float* __restrict__ rb1,
    const float* __restrict__ rga, const float* __restrict__ rbe,
    const float* __restrict__ rw2, const float* __restrict__ rb2,
    const float* __restrict__ cw1, const float* __restrict__ cb1,
    const float* __restrict__ cga, const float* __restrict__ cbe,
    const float* __restrict__ cw2, const float* __restrict__ cb2,
    float* __restrict__ out)
{
    __shared__ float  Er[8 * 110], Ec[8 * 110];      // embed tables, transposed [m][d]
    __shared__ float  cont[4][16 * 50];              // [wave][ch*50 + s]
    __shared__ float4 Rt[4][56];                     // per-wave(query) rotation terms
    __shared__ float  ovs[4][4][128];                // [q][g][m*8+h]

    const int t    = threadIdx.x;
    const int b    = blockIdx.x / 196;
    const int qt   = blockIdx.x % 196;
    const int wave = t >> 6, lane = t & 63;
    const int ij   = qt * 4 + wave;                  // this wave's query
    const int iq   = ij / WDIM, jq = ij % WDIM;
    const float scale = 0.57735026918962576f;        // 1/sqrt(CIN=3)

    // ---- embedding-MLP tables (once per block), transposed to [m][110] ----
    {
        int d = -1;
        const float *w1 = rw1, *b1 = rb1, *ga = rga, *be = rbe, *w2 = rw2, *b2 = rb2;
        float* E = Er;
        if (t < 110) { d = t; }
        else if (t >= 128 && t < 238) { d = t - 128; w1 = cw1; b1 = cb1; ga = cga; be = cbe; w2 = cw2; b2 = cb2; E = Ec; }
        if (d >= 0) {
            float u = (d < 55) ? (-1.0f + (float)d * (2.0f / 54.0f))
                               : -(-1.0f + (float)(d - 55) * (2.0f / 54.0f));
            float hb[16], mu = 0.0f;
#pragma unroll
            for (int c = 0; c < 16; ++c) { hb[c] = u * w1[c] + b1[c]; mu += hb[c]; }
            mu *= (1.0f / 16.0f);
            float var = 0.0f;
#pragma unroll
            for (int c = 0; c < 16; ++c) { float dv = hb[c] - mu; var += dv * dv; }
            var *= (1.0f / 16.0f);
            float rstd = rsqrtf(var + 1e-5f);
#pragma unroll
            for (int c = 0; c < 16; ++c) {
                float hn = ga[c] * (hb[c] - mu) * rstd + be[c];
                hb[c] = hn / (1.0f + __expf(-hn));
            }
#pragma unroll
            for (int m = 0; m < 8; ++m) {
                float e = b2[m];
#pragma unroll
                for (int c = 0; c < 16; ++c) e += hb[c] * w2[m * 16 + c];
                E[m * 110 + d] = e;                  // transposed
            }
        }
    }

    for (int h = 0; h < 8; ++h) {
        __syncthreads();                             // E ready (h=0) + head lockstep
        const int bh = b * 8 + h;

        // q in registers for this (query, head)
        float q[16];
        {
            const float4* qp = (const float4*)(Q + (size_t)(bh * NPOS + ij) * 16);
            float4 q0 = qp[0], q1 = qp[1], q2 = qp[2], q3 = qp[3];
            q[0]=q0.x; q[1]=q0.y; q[2]=q0.z; q[3]=q0.w;
            q[4]=q1.x; q[5]=q1.y; q[6]=q1.z; q[7]=q1.w;
            q[8]=q2.x; q[9]=q2.y; q[10]=q2.z; q[11]=q2.w;
            q[12]=q3.x; q[13]=q3.y; q[14]=q3.z; q[15]=q3.w;
        }

        // packed rotation table Rt[d] = scale*(arow[d], acol[d], arow[d+55], acol[d+55])
        // + per-component maxima for the softmax bound
        float4 myR = make_float4(-3.0e38f, -3.0e38f, -3.0e38f, -3.0e38f);
        if (lane < 55) {
            int d = lane;
            float ar = 0, ac = 0, ar5 = 0, ac5 = 0;
#pragma unroll
            for (int mm = 0; mm < 8; ++mm) {
                float ql = q[mm], qh = q[8 + mm];
                ar  += ql * Er[mm * 110 + d];
                ar5 += ql * Er[mm * 110 + d + 55];
                ac  += qh * Ec[mm * 110 + d];
                ac5 += qh * Ec[mm * 110 + d + 55];
            }
            myR = make_float4(ar * scale, ac * scale, ar5 * scale, ac5 * scale);
            Rt[wave][lane] = myR;
        }
#pragma unroll
        for (int off = 1; off < 64; off <<= 1) {
            myR.x = fmaxf(myR.x, __shfl_xor(myR.x, off, 64));
            myR.y = fmaxf(myR.y, __shfl_xor(myR.y, off, 64));
            myR.z = fmaxf(myR.z, __shfl_xor(myR.z, off, 64));
            myR.w = fmaxf(myR.w, __shfl_xor(myR.w, off, 64));
        }

        // phase A: content pass -> per-wave LDS strip cont[ch*50+s], track max
        float maxc = -3.0e38f;
#pragma unroll
        for (int it = 0; it < 13; ++it) {
            int k = it * 64 + lane;
            if (k < NPOS) {
                const float4* kp = (const float4*)(K + (size_t)(bh * NPOS + k) * 16);
                float4 k0 = kp[0], k1 = kp[1], k2 = kp[2], k3 = kp[3];
                float c = q[0]*k0.x + q[1]*k0.y + q[2]*k0.z + q[3]*k0.w
                        + q[4]*k1.x + q[5]*k1.y + q[6]*k1.z + q[7]*k1.w
                        + q[8]*k2.x + q[9]*k2.y + q[10]*k2.z + q[11]*k2.w
                        + q[12]*k3.x + q[13]*k3.y + q[14]*k3.z + q[15]*k3.w;
                c *= scale;
                cont[wave][(lane & 15) * 50 + (k >> 4)] = c;
                maxc = fmaxf(maxc, c);
            }
        }
#pragma unroll
        for (int off = 1; off < 64; off <<= 1) maxc = fmaxf(maxc, __shfl_xor(maxc, off, 64));

        // phase B: PV. lane = (g = lane>>4, ch = lane&15); keys k = s*16+ch.
        const int g = lane >> 4, ch = lane & 15;
        const float bndrot = ((g == 0) ? myR.x + myR.y :
                              (g == 1) ? myR.y + myR.z :
                              (g == 2) ? myR.z + myR.w :
                                         myR.w + myR.x);
        const float bound = maxc + bndrot;
        const int i1 = g, i2 = (g + 1) & 3;
        const float* RtS = (const float*)&Rt[wave][0];   // scalar view, 4 floats per d
        const float* cw  = &cont[wave][ch * 50];

        float acc[16];
#pragma unroll
        for (int m = 0; m < 16; ++m) acc[m] = 0.0f;
        float ps = 0.0f;
#pragma unroll 2
        for (int s = 0; s < 49; ++s) {
            int k = s * 16 + ch;
            int row = k / WDIM, col = k - row * WDIM;
            float c  = cw[s];
            float tr = RtS[(row - iq + 27) * 4 + i1];
            float tc = RtS[(col - jq + 27) * 4 + i2];
            float p = __expf(c + tr + tc - bound);
            ps += p;
            const float4* vp = (const float4*)(V + (size_t)(bh * NPOS + k) * 16);
            float4 v0 = vp[0], v1 = vp[1], v2 = vp[2], v3 = vp[3];
            acc[0]  += p * v0.x; acc[1]  += p * v0.y; acc[2]  += p * v0.z; acc[3]  += p * v0.w;
            acc[4]  += p * v1.x; acc[5]  += p * v1.y; acc[6]  += p * v1.z; acc[7]  += p * v1.w;
            acc[8]  += p * v2.x; acc[9]  += p * v2.y; acc[10] += p * v2.z; acc[11] += p * v2.w;
            acc[12] += p * v3.x; acc[13] += p * v3.y; acc[14] += p * v3.z; acc[15] += p * v3.w;
        }
#pragma unroll
        for (int off = 1; off < 16; off <<= 1) {
            ps += __shfl_xor(ps, off, 64);
#pragma unroll
            for (int m = 0; m < 16; ++m) acc[m] += __shfl_xor(acc[m], off, 64);
        }
        if (ch == 0) {
            float inv = 1.0f / ps;
#pragma unroll
            for (int m = 0; m < 16; ++m) ovs[wave][g][m * 8 + h] = acc[m] * inv;
        }
    }
    __syncthreads();                                 // all ovs ready

    // ---- output projection: wave = query, lane = o; out (B,64,G,28,28) ----
    {
        int o = lane;
        float a0 = b_out[o], a1 = a0, a2 = a0, a3 = a0;
        const float4* wr = (const float4*)(w_out + o * 128);
        const float* ov0 = ovs[wave][0];
        const float* ov1 = ovs[wave][1];
        const float* ov2 = ovs[wave][2];
        const float* ov3 = ovs[wave][3];
#pragma unroll
        for (int c4 = 0; c4 < 32; ++c4) {
            float4 w4 = wr[c4];
            int c = c4 * 4;
            a0 += w4.x * ov0[c] + w4.y * ov0[c+1] + w4.z * ov0[c+2] + w4.w * ov0[c+3];
            a1 += w4.x * ov1[c] + w4.y * ov1[c+1] + w4.z * ov1[c+2] + w4.w * ov1[c+3];
            a2 += w4.x * ov2[c] + w4.y * ov2[c+1] + w4.z * ov2[c+2] + w4.w * ov2[c+3];
            a3 += w4.x * ov3[c] + w4.y * ov3[c+1] + w4.z * ov3[c+2] + w4.w * ov3[c+3];
        }
        float* op = out + ((size_t)(b * 64 + o) * 4) * NPOS + ij;
        op[0 * NPOS] = a0;
        op[1 * NPOS] = a1;
        op[2 * NPOS] = a2;
        op[3 * NPOS] = a3;
    }
}

extern "C" void kernel_launch(void* const* d_in, const int* in_sizes, int n_in,
                              void* d_out, int out_size, void* d_ws, size_t ws_size,
                              hipStream_t stream)
{
    const float* x     = (const float*)d_in[0];
    const float* wq    = (const float*)d_in[1];
    const float* bq    = (const float*)d_in[2];
    const float* wk    = (const float*)d_in[3];
    const float* bk    = (const float*)d_in[4];
    const float* wv    = (const float*)d_in[5];
    const float* bv    = (const float*)d_in[6];
    const float* w_out = (const float*)d_in[7];
    const float* b_out = (const float*)d_in[8];
    const float* rw1 = (const float*)d_in[9];
    const float* rb1 = (const float*)d_in[10];
    const float* rga = (const float*)d_in[11];
    const float* rbe = (const float*)d_in[12];
    const float* rw2 = (const float*)d_in[13];
    const float* rb2 = (const float*)d_in[14];
    const float* cw1 = (const float*)d_in[15];
    const float* cb1 = (const float*)d_in[16];
    const float* cga = (const float*)d_in[17];
    const float* cbe = (const float*)d_in[18];
    const float* cw2 = (const float*)d_in[19];
    const float* cb2 = (const float*)d_in[20];
    // d_in[21]/d_in[22] (ridx/cidx) unused: closed-form rotation indices.

    float* Q = (float*)d_ws;                 // 3 x 401408 floats = 4.8 MB
    float* K = Q + 401408;
    float* V = K + 401408;

    qkv_kernel<<<1568, 256, 0, stream>>>(x, wq, bq, wk, bk, wv, bv, Q, K, V);
    attn_kernel<<<784, 256, 0, stream>>>(
        Q, K, V, w_out, b_out,
        rw1, rb1, rga, rbe, rw2, rb2,
        cw1, cb1, cga, cbe, cw2, cb2,
        (float*)d_out);
}

// Round 10
// 313.335 us; speedup vs baseline: 1.8765x; 1.8194x over previous
//
#include <hip/hip_runtime.h>
#include <hip/hip_bf16.h>

#define NPOS 784
#define WDIM 28

// ---------------- kernel 1: fused 1x1-conv q/k/v -> d_ws ----------------
// All fp32. Layout [bh][kl][m], m contiguous (16 floats = 64 B per row).
__global__ __launch_bounds__(256) void qkv_kernel(
    const float* __restrict__ x,
    const float* __restrict__ wq, const float* __restrict__ bq,
    const float* __restrict__ wk, const float* __restrict__ bk,
    const float* __restrict__ wv, const float* __restrict__ bv,
    float* __restrict__ Q, float* __restrict__ K, float* __restrict__ V)
{
    int idx = blockIdx.x * 256 + threadIdx.x;        // grid covers exactly 401408
    int ij = idx % NPOS;
    int oc = (idx / NPOS) & 127;
    int b  = idx / (NPOS * 128);

    float x0 = x[(b * 3 + 0) * NPOS + ij];
    float x1 = x[(b * 3 + 1) * NPOS + ij];
    float x2 = x[(b * 3 + 2) * NPOS + ij];

    float q = bq[oc] + wq[oc*3+0]*x0 + wq[oc*3+1]*x1 + wq[oc*3+2]*x2;
    float k = bk[oc] + wk[oc*3+0]*x0 + wk[oc*3+1]*x1 + wk[oc*3+2]*x2;
    float v = bv[oc] + wv[oc*3+0]*x0 + wv[oc*3+1]*x1 + wv[oc*3+2]*x2;

    int m = oc >> 3, h = oc & 7;                     // oc = m*HEADS + h
    int dst = ((b * 8 + h) * NPOS + ij) * 16 + m;
    Q[dst] = q; K[dst] = k; V[dst] = v;
}

// ---------------- kernel 2: attention, block = (b, ij) ----------------
// Wave w owns heads {w, w+4}; no barriers in the head loop. Factorized
// softmax: p_g = ec[k] * er[g] * ecol[(g+1)&3] where ec = exp(c - maxc),
// RtE[d] = exp(rot - maxrot) per component (constants cancel in the
// normalization). PV lane = (vq = lane>>4, ch = lane&15): each lane loads
// only its float4 quarter of V and accumulates all 4 g's.
__global__ __launch_bounds__(256, 4) void attn_kernel(
    const float* __restrict__ Q, const float* __restrict__ K, const float* __restrict__ V,
    const float* __restrict__ w_out, const float* __restrict__ b_out,
    const float* __restrict__ rw1, const float* __restrict__ rb1,
    const float* __restrict__ rga, const float* __restrict__ rbe,
    const float* __restrict__ rw2, const float* __restrict__ rb2,
    const float* __restrict__ cw1, const float* __restrict__ cb1,
    const float* __restrict__ cga, const float* __restrict__ cbe,
    const float* __restrict__ cw2, const float* __restrict__ cb2,
    float* __restrict__ out)
{
    __shared__ float  Er[8 * 110], Ec[8 * 110];      // embed tables, transposed [m][d]
    __shared__ float  cont[4][800];                  // [wave][ch*50 + s]: c, then ec
    __shared__ float4 RtE[4][56];                    // exp'ed rotation terms per wave
    __shared__ float  ovs[8][4][16];                 // [h][g][m]

    const int t    = threadIdx.x;
    const int b    = blockIdx.x / NPOS;
    const int ij   = blockIdx.x % NPOS;
    const int iq   = ij / WDIM, jq = ij % WDIM;
    const int wave = t >> 6, lane = t & 63;
    const float scale = 0.57735026918962576f;        // 1/sqrt(CIN=3)

    // ---- embedding-MLP tables (once per block), transposed to [m][110] ----
    {
        int d = -1;
        const float *w1 = rw1, *b1 = rb1, *ga = rga, *be = rbe, *w2 = rw2, *b2 = rb2;
        float* E = Er;
        if (t < 110) { d = t; }
        else if (t >= 128 && t < 238) { d = t - 128; w1 = cw1; b1 = cb1; ga = cga; be = cbe; w2 = cw2; b2 = cb2; E = Ec; }
        if (d >= 0) {
            float u = (d < 55) ? (-1.0f + (float)d * (2.0f / 54.0f))
                               : -(-1.0f + (float)(d - 55) * (2.0f / 54.0f));
            float hb[16], mu = 0.0f;
#pragma unroll
            for (int c = 0; c < 16; ++c) { hb[c] = u * w1[c] + b1[c]; mu += hb[c]; }
            mu *= (1.0f / 16.0f);
            float var = 0.0f;
#pragma unroll
            for (int c = 0; c < 16; ++c) { float dv = hb[c] - mu; var += dv * dv; }
            var *= (1.0f / 16.0f);
            float rstd = rsqrtf(var + 1e-5f);
#pragma unroll
            for (int c = 0; c < 16; ++c) {
                float hn = ga[c] * (hb[c] - mu) * rstd + be[c];
                hb[c] = hn / (1.0f + __expf(-hn));
            }
#pragma unroll
            for (int m = 0; m < 8; ++m) {
                float e = b2[m];
#pragma unroll
                for (int c = 0; c < 16; ++c) e += hb[c] * w2[m * 16 + c];
                E[m * 110 + d] = e;                  // transposed
            }
        }
    }
    __syncthreads();                                 // E ready for all waves

    for (int hi = 0; hi < 2; ++hi) {
        const int h  = wave + hi * 4;
        const int bh = b * 8 + h;

        // q in registers (wave-uniform loads, L2-hot)
        float q[16];
        {
            const float4* qp = (const float4*)(Q + (size_t)(bh * NPOS + ij) * 16);
            float4 q0 = qp[0], q1 = qp[1], q2 = qp[2], q3 = qp[3];
            q[0]=q0.x; q[1]=q0.y; q[2]=q0.z; q[3]=q0.w;
            q[4]=q1.x; q[5]=q1.y; q[6]=q1.z; q[7]=q1.w;
            q[8]=q2.x; q[9]=q2.y; q[10]=q2.z; q[11]=q2.w;
            q[12]=q3.x; q[13]=q3.y; q[14]=q3.z; q[15]=q3.w;
        }

        // rotation terms (scaled) + per-component maxima -> exp'ed table
        float4 mine = make_float4(-3.0e38f, -3.0e38f, -3.0e38f, -3.0e38f);
        if (lane < 55) {
            int d = lane;
            float ar = 0, ac = 0, ar5 = 0, ac5 = 0;
#pragma unroll
            for (int mm = 0; mm < 8; ++mm) {
                float ql = q[mm], qh = q[8 + mm];
                ar  += ql * Er[mm * 110 + d];
                ar5 += ql * Er[mm * 110 + d + 55];
                ac  += qh * Ec[mm * 110 + d];
                ac5 += qh * Ec[mm * 110 + d + 55];
            }
            mine = make_float4(ar * scale, ac * scale, ar5 * scale, ac5 * scale);
        }
        float4 mx = mine;
#pragma unroll
        for (int off = 1; off < 64; off <<= 1) {
            mx.x = fmaxf(mx.x, __shfl_xor(mx.x, off, 64));
            mx.y = fmaxf(mx.y, __shfl_xor(mx.y, off, 64));
            mx.z = fmaxf(mx.z, __shfl_xor(mx.z, off, 64));
            mx.w = fmaxf(mx.w, __shfl_xor(mx.w, off, 64));
        }
        if (lane < 55)
            RtE[wave][lane] = make_float4(__expf(mine.x - mx.x), __expf(mine.y - mx.y),
                                          __expf(mine.z - mx.z), __expf(mine.w - mx.w));

        // content pass -> strip cont[ch*50+s]; track max
        float maxc = -3.0e38f;
#pragma unroll 4
        for (int it = 0; it < 13; ++it) {
            int k = it * 64 + lane;
            if (k < NPOS) {
                const float4* kp = (const float4*)(K + (size_t)(bh * NPOS + k) * 16);
                float4 k0 = kp[0], k1 = kp[1], k2 = kp[2], k3 = kp[3];
                float c = q[0]*k0.x + q[1]*k0.y + q[2]*k0.z + q[3]*k0.w
                        + q[4]*k1.x + q[5]*k1.y + q[6]*k1.z + q[7]*k1.w
                        + q[8]*k2.x + q[9]*k2.y + q[10]*k2.z + q[11]*k2.w
                        + q[12]*k3.x + q[13]*k3.y + q[14]*k3.z + q[15]*k3.w;
                c *= scale;
                cont[wave][(k & 15) * 50 + (k >> 4)] = c;
                maxc = fmaxf(maxc, c);
            }
        }
#pragma unroll
        for (int off = 1; off < 64; off <<= 1) maxc = fmaxf(maxc, __shfl_xor(maxc, off, 64));

        // exp-ify the strip (same-wave RMW, in-order, no barrier)
#pragma unroll 4
        for (int it = 0; it < 13; ++it) {
            int idx = it * 64 + lane;
            if (idx < 800) {
                float cv = cont[wave][idx];
                cont[wave][idx] = __expf(cv - maxc);
            }
        }

        // PV: lane = (vq, ch); keys k = s*16+ch; 3 mults per p, no exp.
        const int vq = lane >> 4, ch = lane & 15;
        const float*  ecw  = &cont[wave][ch * 50];
        const float4* RtEp = &RtE[wave][0];
        float acc[4][4];
#pragma unroll
        for (int g = 0; g < 4; ++g)
#pragma unroll
            for (int c = 0; c < 4; ++c) acc[g][c] = 0.0f;
        float ps0 = 0, ps1 = 0, ps2 = 0, ps3 = 0;
#pragma unroll 4
        for (int s = 0; s < 49; ++s) {
            int k   = s * 16 + ch;
            int row = (k * 2341) >> 16;              // k / 28 (exact for k < 784)
            int col = k - row * WDIM;
            float  ec   = ecw[s];                    // broadcast across vq groups
            float4 er   = RtEp[row - iq + 27];
            float4 ecol = RtEp[col - jq + 27];
            float p0 = ec * er.x * ecol.y;
            float p1 = ec * er.y * ecol.z;
            float p2 = ec * er.z * ecol.w;
            float p3 = ec * er.w * ecol.x;
            ps0 += p0; ps1 += p1; ps2 += p2; ps3 += p3;
            float4 v = ((const float4*)(V + (size_t)(bh * NPOS + k) * 16))[vq];
            acc[0][0] += p0*v.x; acc[0][1] += p0*v.y; acc[0][2] += p0*v.z; acc[0][3] += p0*v.w;
            acc[1][0] += p1*v.x; acc[1][1] += p1*v.y; acc[1][2] += p1*v.z; acc[1][3] += p1*v.w;
            acc[2][0] += p2*v.x; acc[2][1] += p2*v.y; acc[2][2] += p2*v.z; acc[2][3] += p2*v.w;
            acc[3][0] += p3*v.x; acc[3][1] += p3*v.y; acc[3][2] += p3*v.z; acc[3][3] += p3*v.w;
        }
        // reduce over the 16 ch lanes (xor stays within each vq group)
#pragma unroll
        for (int off = 1; off < 16; off <<= 1) {
            ps0 += __shfl_xor(ps0, off, 64); ps1 += __shfl_xor(ps1, off, 64);
            ps2 += __shfl_xor(ps2, off, 64); ps3 += __shfl_xor(ps3, off, 64);
#pragma unroll
            for (int g = 0; g < 4; ++g)
#pragma unroll
                for (int c = 0; c < 4; ++c) acc[g][c] += __shfl_xor(acc[g][c], off, 64);
        }
        if (ch == 0) {
            float inv0 = 1.0f / ps0, inv1 = 1.0f / ps1, inv2 = 1.0f / ps2, inv3 = 1.0f / ps3;
#pragma unroll
            for (int c = 0; c < 4; ++c) {
                ovs[h][0][vq * 4 + c] = acc[0][c] * inv0;
                ovs[h][1][vq * 4 + c] = acc[1][c] * inv1;
                ovs[h][2][vq * 4 + c] = acc[2][c] * inv2;
                ovs[h][3][vq * 4 + c] = acc[3][c] * inv3;
            }
        }
    }
    __syncthreads();                                 // all ovs ready

    // ---- output projection: thread = (o = t>>2, g = t&3); out (B,64,G,28,28) ----
    {
        int o = t >> 2, g = t & 3;
        float acc = b_out[o];
        const float4* wr = (const float4*)(w_out + o * 128);
#pragma unroll
        for (int c4 = 0; c4 < 32; ++c4) {
            float4 w4 = wr[c4];
            int c = c4 * 4;                          // mh = m*8 + h
            acc += w4.x * ovs[(c    ) & 7][g][(c    ) >> 3];
            acc += w4.y * ovs[(c + 1) & 7][g][(c + 1) >> 3];
            acc += w4.z * ovs[(c + 2) & 7][g][(c + 2) >> 3];
            acc += w4.w * ovs[(c + 3) & 7][g][(c + 3) >> 3];
        }
        out[((b * 64 + o) * 4 + g) * NPOS + ij] = acc;
    }
}

extern "C" void kernel_launch(void* const* d_in, const int* in_sizes, int n_in,
                              void* d_out, int out_size, void* d_ws, size_t ws_size,
                              hipStream_t stream)
{
    const float* x     = (const float*)d_in[0];
    const float* wq    = (const float*)d_in[1];
    const float* bq    = (const float*)d_in[2];
    const float* wk    = (const float*)d_in[3];
    const float* bk    = (const float*)d_in[4];
    const float* wv    = (const float*)d_in[5];
    const float* bv    = (const float*)d_in[6];
    const float* w_out = (const float*)d_in[7];
    const float* b_out = (const float*)d_in[8];
    const float* rw1 = (const float*)d_in[9];
    const float* rb1 = (const float*)d_in[10];
    const float* rga = (const float*)d_in[11];
    const float* rbe = (const float*)d_in[12];
    const float* rw2 = (const float*)d_in[13];
    const float* rb2 = (const float*)d_in[14];
    const float* cw1 = (const float*)d_in[15];
    const float* cb1 = (const float*)d_in[16];
    const float* cga = (const float*)d_in[17];
    const float* cbe = (const float*)d_in[18];
    const float* cw2 = (const float*)d_in[19];
    const float* cb2 = (const float*)d_in[20];
    // d_in[21]/d_in[22] (ridx/cidx) unused: closed-form rotation indices.

    float* Q = (float*)d_ws;                 // 3 x 401408 floats = 4.8 MB
    float* K = Q + 401408;
    float* V = K + 401408;

    qkv_kernel<<<1568, 256, 0, stream>>>(x, wq, bq, wk, bk, wv, bv, Q, K, V);
    attn_kernel<<<4 * NPOS, 256, 0, stream>>>(
        Q, K, V, w_out, b_out,
        rw1, rb1, rga, rbe, rw2, rb2,
        cw1, cb1, cga, cbe, cw2, cb2,
        (float*)d_out);
}